// Round 13
// baseline (92.359 us; speedup 1.0000x reference)
//
#include <hip/hip_runtime.h>
#include <math.h>

// Problem constants (B=2, T=4096, n=4, D=2048)
#define DM      8192      // n*D flattened feature dim
#define NTOK    8192      // B*T tokens
#define NKS     256       // k-steps of 32 d over DM
#define TPB_C   256

typedef _Float16 f16x8 __attribute__((ext_vector_type(8)));
typedef float    f32x4 __attribute__((ext_vector_type(4)));

// nontemporal float4 load: x is strict read-once streaming data; keeping it
// out of L2 preserves the Wh working set (512 KB) in each XCD's L2.
// NOTE: __builtin_nontemporal_load requires a NATIVE clang vector type —
// HIP's float4 (HIP_vector_type struct) does not compile (R12).
__device__ __forceinline__ f32x4 ldnt(const float* p) {
    return __builtin_nontemporal_load((const f32x4*)p);
}

// ---------------------------------------------------------------------------
// Kernel 1: weight fragments, f16.
// Wh[kstep][frag][lane][i] = alpha_c * W_c[d] * rms_w[d], where
//   c = frag*16 + (lane&15)   (c>=24 -> 0 pad)
//   d = kstep*32 + (lane>>4)*8 + i
// Exactly the B-operand lane layout of mfma_f32_16x16x32_f16, so the main
// kernel loads one b128 per fragment. 512 KB, L2/L3-resident.
// ---------------------------------------------------------------------------
__global__ void combine_w(const float* __restrict__ rms_w,
                          const float* __restrict__ w_pre,
                          const float* __restrict__ w_post,
                          const float* __restrict__ w_res,
                          const float* __restrict__ a_pre,
                          const float* __restrict__ a_post,
                          const float* __restrict__ a_res,
                          _Float16* __restrict__ Wh) {
    const int idx = blockIdx.x * blockDim.x + threadIdx.x;
    if (idx >= NKS * 2 * 64 * 8) return;
    const int i  = idx & 7;
    const int l  = (idx >> 3) & 63;
    const int f  = (idx >> 9) & 1;
    const int ks = idx >> 10;
    const int c  = f * 16 + (l & 15);
    const int d  = ks * 32 + (l >> 4) * 8 + i;
    float v = 0.0f;
    if (c < 24) {
        float w, a;
        if (c < 4)      { w = w_pre [(size_t)c       * DM + d]; a = a_pre[0];  }
        else if (c < 8) { w = w_post[(size_t)(c - 4) * DM + d]; a = a_post[0]; }
        else            { w = w_res [(size_t)(c - 8) * DM + d]; a = a_res[0];  }
        v = a * w * rms_w[d];
    }
    Wh[idx] = (_Float16)v;
}

// ---------------------------------------------------------------------------
// Kernel 2: FUSED dots + rms + sigmoid + Sinkhorn. Block = 16 tokens, 8 waves.
//  Wave wv owns d-range [wv*1024, (wv+1)*1024) = 32 k-steps of 32 d.
//  Per step: A-frag = x rows fp32->f16 (RNE scalar cvt), B-frags from Wh
//  (b128), 2x mfma_f32_16x16x32_f16, fp32 ss on VALU (exact).
//  s-loop unroll-4: deepens in-flight loads to cover ~900cyc HBM latency
//  at 16 waves/CU. FP order per accumulator chain unchanged.
//  D-frag: lane l reg r -> (tok=(l>>4)*4+r, coeff=l&15) [m89 layout].
// ---------------------------------------------------------------------------
__global__ __launch_bounds__(512) void fused_k(const float* __restrict__ x,
                                               const _Float16* __restrict__ Wh,
                                               const float* __restrict__ b_pre,
                                               const float* __restrict__ b_post,
                                               const float* __restrict__ b_res,
                                               float* __restrict__ out) {
    __shared__ float ldsA[2][8 * 256];   // [frag][wave*256 + lane*4 + reg]
    __shared__ float ldsS[8][16];        // [wave][tok] ss partials
    __shared__ float ldsF[16 * 28];      // [tok][28] final sums (24 dots + ss)

    const int t    = threadIdx.x;
    const int wv   = t >> 6;             // 0..7
    const int l    = t & 63;
    const int row  = l & 15;             // token row within tile
    const int kg   = l >> 4;             // k-group 0..3
    const int tok0 = blockIdx.x * 16;

    const float* xr = x + (size_t)(tok0 + row) * DM + wv * 1024 + kg * 8;
    const _Float16* wb = Wh + (size_t)wv * 32 * 1024;   // wv*32 ksteps * 1024

    f32x4 acc0 = {0.f, 0.f, 0.f, 0.f};
    f32x4 acc1 = {0.f, 0.f, 0.f, 0.f};
    float ss = 0.0f;

#pragma unroll 4
    for (int s = 0; s < 32; ++s) {
        const f32x4 xa = ldnt(xr + s * 32);
        const f32x4 xb = ldnt(xr + s * 32 + 4);
        const f16x8 b0 = *(const f16x8*)(wb + ((s * 2 + 0) * 64 + l) * 8);
        const f16x8 b1 = *(const f16x8*)(wb + ((s * 2 + 1) * 64 + l) * 8);
        f16x8 af;
        af[0] = (_Float16)xa[0]; af[1] = (_Float16)xa[1];
        af[2] = (_Float16)xa[2]; af[3] = (_Float16)xa[3];
        af[4] = (_Float16)xb[0]; af[5] = (_Float16)xb[1];
        af[6] = (_Float16)xb[2]; af[7] = (_Float16)xb[3];
        acc0 = __builtin_amdgcn_mfma_f32_16x16x32_f16(af, b0, acc0, 0, 0, 0);
        acc1 = __builtin_amdgcn_mfma_f32_16x16x32_f16(af, b1, acc1, 0, 0, 0);
        ss = fmaf(xa[0], xa[0], ss); ss = fmaf(xa[1], xa[1], ss);
        ss = fmaf(xa[2], xa[2], ss); ss = fmaf(xa[3], xa[3], ss);
        ss = fmaf(xb[0], xb[0], ss); ss = fmaf(xb[1], xb[1], ss);
        ss = fmaf(xb[2], xb[2], ss); ss = fmaf(xb[3], xb[3], ss);
    }

    // ss: fold the 4 k-groups (lanes row, row+16, row+32, row+48)
    ss += __shfl_xor(ss, 16);
    ss += __shfl_xor(ss, 32);
    if (l < 16) ldsS[wv][l] = ss;

    *(f32x4*)&ldsA[0][wv * 256 + l * 4] = acc0;
    *(f32x4*)&ldsA[1][wv * 256 + l * 4] = acc1;
    __syncthreads();

    // ---- cross-wave reduce: 384 dot jobs + 16 ss jobs -> ldsF ----
    if (t < 384) {
        const int tok = t / 24;
        const int c   = t - tok * 24;
        const int fi  = (c < 16) ? 0 : 1;
        const int src = ((tok >> 2) << 4) | (c & 15);   // D-frag lane
        const int reg = tok & 3;                         // D-frag reg
        float v = 0.0f;
#pragma unroll
        for (int w = 0; w < 8; ++w)
            v += ldsA[fi][w * 256 + src * 4 + reg];
        ldsF[tok * 28 + c] = v;
    } else if (t < 400) {
        const int tok = t - 384;
        float v = 0.0f;
#pragma unroll
        for (int w = 0; w < 8; ++w) v += ldsS[w][tok];
        ldsF[tok * 28 + 24] = v;
    }
    __syncthreads();

    // ---- epilogue: wave 0, 16 tok x 4 gq (duplicated math, split writes) ----
    if (t < 64) {
        const int tok = t >> 2;
        const int gq  = t & 3;
        const int tk  = tok0 + tok;

        float v[28];
#pragma unroll
        for (int q = 0; q < 7; ++q)
            *(float4*)&v[q * 4] = *(const float4*)&ldsF[tok * 28 + q * 4];

        const float rstd = rsqrtf(v[24] * (1.0f / (float)DM) + 1e-6f);

        float hp[4], hq[4];
#pragma unroll
        for (int j = 0; j < 4; ++j) {
            const float lp = fmaf(v[j], rstd, b_pre[j]);
            hp[j] = 1.0f / (1.0f + expf(-lp));
            const float lq = fmaf(v[4 + j], rstd, b_post[j]);
            hq[j] = 2.0f / (1.0f + expf(-lq));
        }

        // Sinkhorn-Knopp 4x4 in registers (rcpf validated R7-R11)
        float M[4][4];
#pragma unroll
        for (int i = 0; i < 4; ++i) {
            float lg[4];
#pragma unroll
            for (int j = 0; j < 4; ++j)
                lg[j] = fmaf(v[8 + i * 4 + j], rstd, b_res[i * 4 + j]);
            const float m = fmaxf(fmaxf(lg[0], lg[1]), fmaxf(lg[2], lg[3]));
#pragma unroll
            for (int j = 0; j < 4; ++j)
                M[i][j] = fmaxf(expf(lg[j] - m), 1e-6f);
        }
        for (int it = 0; it < 20; ++it) {
#pragma unroll
            for (int i = 0; i < 4; ++i) {
                const float s = (M[i][0] + M[i][1]) + (M[i][2] + M[i][3]);
                const float inv = __builtin_amdgcn_rcpf(fmaxf(s, 1e-6f));
#pragma unroll
                for (int j = 0; j < 4; ++j) M[i][j] *= inv;
            }
#pragma unroll
            for (int j = 0; j < 4; ++j) {
                const float s = (M[0][j] + M[1][j]) + (M[2][j] + M[3][j]);
                const float inv = __builtin_amdgcn_rcpf(fmaxf(s, 1e-6f));
#pragma unroll
                for (int i = 0; i < 4; ++i) M[i][j] *= inv;
            }
        }

        float* out_pre  = out;                        // [NTOK][4]
        float* out_post = out + (size_t)NTOK * 4;     // [NTOK][4]
        float* out_res  = out + (size_t)NTOK * 8;     // [NTOK][16]
        if (gq == 0) {
            ((float4*)out_pre)[tk] = make_float4(hp[0], hp[1], hp[2], hp[3]);
        } else if (gq == 1) {
            ((float4*)out_post)[tk] = make_float4(hq[0], hq[1], hq[2], hq[3]);
        } else if (gq == 2) {
            ((float4*)out_res)[tk * 4 + 0] = make_float4(M[0][0], M[0][1], M[0][2], M[0][3]);
            ((float4*)out_res)[tk * 4 + 1] = make_float4(M[1][0], M[1][1], M[1][2], M[1][3]);
        } else {
            ((float4*)out_res)[tk * 4 + 2] = make_float4(M[2][0], M[2][1], M[2][2], M[2][3]);
            ((float4*)out_res)[tk * 4 + 3] = make_float4(M[3][0], M[3][1], M[3][2], M[3][3]);
        }
    }
}

// ---------------------------------------------------------------------------
extern "C" void kernel_launch(void* const* d_in, const int* in_sizes, int n_in,
                              void* d_out, int out_size, void* d_ws, size_t ws_size,
                              hipStream_t stream) {
    const float* x      = (const float*)d_in[0];   // (2,4096,4,2048) fp32
    const float* rms_w  = (const float*)d_in[1];   // (8192,)
    const float* w_pre  = (const float*)d_in[2];   // (4,8192)
    const float* w_post = (const float*)d_in[3];   // (4,8192)
    const float* w_res  = (const float*)d_in[4];   // (16,8192)
    const float* b_pre  = (const float*)d_in[5];   // (4,)
    const float* b_post = (const float*)d_in[6];   // (4,)
    const float* b_res  = (const float*)d_in[7];   // (4,4)
    const float* a_pre  = (const float*)d_in[8];   // scalar
    const float* a_post = (const float*)d_in[9];   // scalar
    const float* a_res  = (const float*)d_in[10];  // scalar
    float* out = (float*)d_out;

    _Float16* Wh = (_Float16*)d_ws;                // 512 KB of ws

    combine_w<<<(NKS * 2 * 64 * 8 + TPB_C - 1) / TPB_C, TPB_C, 0, stream>>>(
        rms_w, w_pre, w_post, w_res, a_pre, a_post, a_res, Wh);

    fused_k<<<NTOK / 16, 512, 0, stream>>>(x, Wh, b_pre, b_post, b_res, out);
}

// Round 14
// 57.224 us; speedup vs baseline: 1.6140x; 1.6140x over previous
//
#include <hip/hip_runtime.h>
#include <math.h>

// Problem constants (B=2, T=4096, n=4, D=2048)
#define DM      8192      // n*D flattened feature dim
#define NTOK    8192      // B*T tokens
#define NKS     256       // k-steps of 32 d over DM
#define TPB_C   256

typedef _Float16 f16x8 __attribute__((ext_vector_type(8)));
typedef float    f32x4 __attribute__((ext_vector_type(4)));

// ---------------------------------------------------------------------------
// Kernel 1: weight fragments, f16.
// Wh[kstep][frag][lane][i] = alpha_c * W_c[d] * rms_w[d], where
//   c = frag*16 + (lane&15)   (c>=24 -> 0 pad)
//   d = kstep*32 + (lane>>4)*8 + i
// Exactly the B-operand lane layout of mfma_f32_16x16x32_f16, so the main
// kernel loads one b128 per fragment. 512 KB, L2/L3-resident.
// ---------------------------------------------------------------------------
__global__ void combine_w(const float* __restrict__ rms_w,
                          const float* __restrict__ w_pre,
                          const float* __restrict__ w_post,
                          const float* __restrict__ w_res,
                          const float* __restrict__ a_pre,
                          const float* __restrict__ a_post,
                          const float* __restrict__ a_res,
                          _Float16* __restrict__ Wh) {
    const int idx = blockIdx.x * blockDim.x + threadIdx.x;
    if (idx >= NKS * 2 * 64 * 8) return;
    const int i  = idx & 7;
    const int l  = (idx >> 3) & 63;
    const int f  = (idx >> 9) & 1;
    const int ks = idx >> 10;
    const int c  = f * 16 + (l & 15);
    const int d  = ks * 32 + (l >> 4) * 8 + i;
    float v = 0.0f;
    if (c < 24) {
        float w, a;
        if (c < 4)      { w = w_pre [(size_t)c       * DM + d]; a = a_pre[0];  }
        else if (c < 8) { w = w_post[(size_t)(c - 4) * DM + d]; a = a_post[0]; }
        else            { w = w_res [(size_t)(c - 8) * DM + d]; a = a_res[0];  }
        v = a * w * rms_w[d];
    }
    Wh[idx] = (_Float16)v;
}

// ---------------------------------------------------------------------------
// Kernel 2: FUSED dots + rms + sigmoid + Sinkhorn. Block = 16 tokens, 8 waves.
//  EXACT R11 build (57.0 us) — reverted after R13's unroll-4 + nontemporal
//  experiment regressed to 92.4 us (register-pressure/occupancy + defeated
//  L1 segment reuse). Natural compiler schedule + 16 waves/CU covers HBM
//  latency; do NOT deepen the pipeline or mark x loads nontemporal.
//  Wave wv owns d-range [wv*1024, (wv+1)*1024) = 32 k-steps of 32 d.
//  Per step: A-frag = x rows fp32->f16 (RNE scalar cvt), B-frags from Wh
//  (b128), 2x mfma_f32_16x16x32_f16, fp32 ss on VALU (exact).
//  D-frag: lane l reg r -> (tok=(l>>4)*4+r, coeff=l&15) [m89 layout].
// ---------------------------------------------------------------------------
__global__ __launch_bounds__(512) void fused_k(const float* __restrict__ x,
                                               const _Float16* __restrict__ Wh,
                                               const float* __restrict__ b_pre,
                                               const float* __restrict__ b_post,
                                               const float* __restrict__ b_res,
                                               float* __restrict__ out) {
    __shared__ float ldsA[2][8 * 256];   // [frag][wave*256 + lane*4 + reg]
    __shared__ float ldsS[8][16];        // [wave][tok] ss partials
    __shared__ float ldsF[16 * 28];      // [tok][28] final sums (24 dots + ss)

    const int t    = threadIdx.x;
    const int wv   = t >> 6;             // 0..7
    const int l    = t & 63;
    const int row  = l & 15;             // token row within tile
    const int kg   = l >> 4;             // k-group 0..3
    const int tok0 = blockIdx.x * 16;

    const float* xr = x + (size_t)(tok0 + row) * DM + wv * 1024 + kg * 8;
    const _Float16* wb = Wh + (size_t)wv * 32 * 1024;   // wv*32 ksteps * 1024

    f32x4 acc0 = {0.f, 0.f, 0.f, 0.f};
    f32x4 acc1 = {0.f, 0.f, 0.f, 0.f};
    float ss = 0.0f;

    for (int s = 0; s < 32; ++s) {
        const float4 xa = *(const float4*)(xr + s * 32);
        const float4 xb = *(const float4*)(xr + s * 32 + 4);
        const f16x8 b0 = *(const f16x8*)(wb + ((s * 2 + 0) * 64 + l) * 8);
        const f16x8 b1 = *(const f16x8*)(wb + ((s * 2 + 1) * 64 + l) * 8);
        f16x8 af;
        af[0] = (_Float16)xa.x; af[1] = (_Float16)xa.y;
        af[2] = (_Float16)xa.z; af[3] = (_Float16)xa.w;
        af[4] = (_Float16)xb.x; af[5] = (_Float16)xb.y;
        af[6] = (_Float16)xb.z; af[7] = (_Float16)xb.w;
        acc0 = __builtin_amdgcn_mfma_f32_16x16x32_f16(af, b0, acc0, 0, 0, 0);
        acc1 = __builtin_amdgcn_mfma_f32_16x16x32_f16(af, b1, acc1, 0, 0, 0);
        ss = fmaf(xa.x, xa.x, ss); ss = fmaf(xa.y, xa.y, ss);
        ss = fmaf(xa.z, xa.z, ss); ss = fmaf(xa.w, xa.w, ss);
        ss = fmaf(xb.x, xb.x, ss); ss = fmaf(xb.y, xb.y, ss);
        ss = fmaf(xb.z, xb.z, ss); ss = fmaf(xb.w, xb.w, ss);
    }

    // ss: fold the 4 k-groups (lanes row, row+16, row+32, row+48)
    ss += __shfl_xor(ss, 16);
    ss += __shfl_xor(ss, 32);
    if (l < 16) ldsS[wv][l] = ss;

    *(f32x4*)&ldsA[0][wv * 256 + l * 4] = acc0;
    *(f32x4*)&ldsA[1][wv * 256 + l * 4] = acc1;
    __syncthreads();

    // ---- cross-wave reduce: 384 dot jobs + 16 ss jobs -> ldsF ----
    if (t < 384) {
        const int tok = t / 24;
        const int c   = t - tok * 24;
        const int fi  = (c < 16) ? 0 : 1;
        const int src = ((tok >> 2) << 4) | (c & 15);   // D-frag lane
        const int reg = tok & 3;                         // D-frag reg
        float v = 0.0f;
#pragma unroll
        for (int w = 0; w < 8; ++w)
            v += ldsA[fi][w * 256 + src * 4 + reg];
        ldsF[tok * 28 + c] = v;
    } else if (t < 400) {
        const int tok = t - 384;
        float v = 0.0f;
#pragma unroll
        for (int w = 0; w < 8; ++w) v += ldsS[w][tok];
        ldsF[tok * 28 + 24] = v;
    }
    __syncthreads();

    // ---- epilogue: wave 0, 16 tok x 4 gq (duplicated math, split writes) ----
    if (t < 64) {
        const int tok = t >> 2;
        const int gq  = t & 3;
        const int tk  = tok0 + tok;

        float v[28];
#pragma unroll
        for (int q = 0; q < 7; ++q)
            *(float4*)&v[q * 4] = *(const float4*)&ldsF[tok * 28 + q * 4];

        const float rstd = rsqrtf(v[24] * (1.0f / (float)DM) + 1e-6f);

        float hp[4], hq[4];
#pragma unroll
        for (int j = 0; j < 4; ++j) {
            const float lp = fmaf(v[j], rstd, b_pre[j]);
            hp[j] = 1.0f / (1.0f + expf(-lp));
            const float lq = fmaf(v[4 + j], rstd, b_post[j]);
            hq[j] = 2.0f / (1.0f + expf(-lq));
        }

        // Sinkhorn-Knopp 4x4 in registers (rcpf validated R7-R11)
        float M[4][4];
#pragma unroll
        for (int i = 0; i < 4; ++i) {
            float lg[4];
#pragma unroll
            for (int j = 0; j < 4; ++j)
                lg[j] = fmaf(v[8 + i * 4 + j], rstd, b_res[i * 4 + j]);
            const float m = fmaxf(fmaxf(lg[0], lg[1]), fmaxf(lg[2], lg[3]));
#pragma unroll
            for (int j = 0; j < 4; ++j)
                M[i][j] = fmaxf(expf(lg[j] - m), 1e-6f);
        }
        for (int it = 0; it < 20; ++it) {
#pragma unroll
            for (int i = 0; i < 4; ++i) {
                const float s = (M[i][0] + M[i][1]) + (M[i][2] + M[i][3]);
                const float inv = __builtin_amdgcn_rcpf(fmaxf(s, 1e-6f));
#pragma unroll
                for (int j = 0; j < 4; ++j) M[i][j] *= inv;
            }
#pragma unroll
            for (int j = 0; j < 4; ++j) {
                const float s = (M[0][j] + M[1][j]) + (M[2][j] + M[3][j]);
                const float inv = __builtin_amdgcn_rcpf(fmaxf(s, 1e-6f));
#pragma unroll
                for (int i = 0; i < 4; ++i) M[i][j] *= inv;
            }
        }

        float* out_pre  = out;                        // [NTOK][4]
        float* out_post = out + (size_t)NTOK * 4;     // [NTOK][4]
        float* out_res  = out + (size_t)NTOK * 8;     // [NTOK][16]
        if (gq == 0) {
            ((float4*)out_pre)[tk] = make_float4(hp[0], hp[1], hp[2], hp[3]);
        } else if (gq == 1) {
            ((float4*)out_post)[tk] = make_float4(hq[0], hq[1], hq[2], hq[3]);
        } else if (gq == 2) {
            ((float4*)out_res)[tk * 4 + 0] = make_float4(M[0][0], M[0][1], M[0][2], M[0][3]);
            ((float4*)out_res)[tk * 4 + 1] = make_float4(M[1][0], M[1][1], M[1][2], M[1][3]);
        } else {
            ((float4*)out_res)[tk * 4 + 2] = make_float4(M[2][0], M[2][1], M[2][2], M[2][3]);
            ((float4*)out_res)[tk * 4 + 3] = make_float4(M[3][0], M[3][1], M[3][2], M[3][3]);
        }
    }
}

// ---------------------------------------------------------------------------
extern "C" void kernel_launch(void* const* d_in, const int* in_sizes, int n_in,
                              void* d_out, int out_size, void* d_ws, size_t ws_size,
                              hipStream_t stream) {
    const float* x      = (const float*)d_in[0];   // (2,4096,4,2048) fp32
    const float* rms_w  = (const float*)d_in[1];   // (8192,)
    const float* w_pre  = (const float*)d_in[2];   // (4,8192)
    const float* w_post = (const float*)d_in[3];   // (4,8192)
    const float* w_res  = (const float*)d_in[4];   // (16,8192)
    const float* b_pre  = (const float*)d_in[5];   // (4,)
    const float* b_post = (const float*)d_in[6];   // (4,)
    const float* b_res  = (const float*)d_in[7];   // (4,4)
    const float* a_pre  = (const float*)d_in[8];   // scalar
    const float* a_post = (const float*)d_in[9];   // scalar
    const float* a_res  = (const float*)d_in[10];  // scalar
    float* out = (float*)d_out;

    _Float16* Wh = (_Float16*)d_ws;                // 512 KB of ws

    combine_w<<<(NKS * 2 * 64 * 8 + TPB_C - 1) / TPB_C, TPB_C, 0, stream>>>(
        rms_w, w_pre, w_post, w_res, a_pre, a_post, a_res, Wh);

    fused_k<<<NTOK / 16, 512, 0, stream>>>(x, Wh, b_pre, b_post, b_res, out);
}